// Round 13
// baseline (343.661 us; speedup 1.0000x reference)
//
#include <hip/hip_runtime.h>

typedef unsigned short u16;
typedef unsigned int u32;
typedef __attribute__((ext_vector_type(8))) short short8;
typedef __attribute__((ext_vector_type(4))) short short4v;
typedef __attribute__((ext_vector_type(4))) float f32x4;

__device__ __forceinline__ u16 f2bf(float f) {
    u32 u = __float_as_uint(f);
    u32 r = (u + 0x7fffu + ((u >> 16) & 1u)) >> 16;   // RNE
    return (u16)r;
}
__device__ __forceinline__ float bf2f(u16 h) {
    return __uint_as_float(((u32)h) << 16);
}

__device__ __forceinline__ void gload_lds16(const void* g, void* l) {
    __builtin_amdgcn_global_load_lds((const __attribute__((address_space(1))) void*)g,
                                     (__attribute__((address_space(3))) void*)l, 16, 0, 0);
}

// fence-only barrier: __syncthreads gives workgroup fences (orders LDS +
// global_load_lds across it) WITHOUT sched_barrier(0) walls — lets the
// scheduler interleave addr calc / read issue / MFMA across phase edges.
#define BARRIER() __syncthreads()
#define VMCNT(N)  asm volatile("s_waitcnt vmcnt(" #N ")" ::: "memory")

// stage one 128-row half (2 global_load_lds per thread; dest linear, src inverse-swizzled)
#define STAGE(ptr, LDG, LOFF, RBASE, kelem) \
    do { gload_lds16((ptr) + (size_t)(RBASE) * (LDG) + (kelem),        lds + (LOFF) + ((RBASE) + (wid << 3)) * 128); \
         gload_lds16((ptr) + (size_t)((RBASE) + 64) * (LDG) + (kelem), lds + (LOFF) + ((RBASE) + 64 + (wid << 3)) * 128); } while (0)

template<int ROFF, int QH>
__device__ __forceinline__ void ld_a(short8 (&a)[4][2], const char* lds, int arow, int c0, int c1) {
    #pragma unroll
    for (int mf = 0; mf < 4; ++mf) {
        a[mf][0] = *(const short8*)(lds + ROFF + QH * 16384 + mf * 2048 + arow + c0);
        a[mf][1] = *(const short8*)(lds + ROFF + QH * 16384 + mf * 2048 + arow + c1);
    }
}
template<int ROFF, int QH>
__device__ __forceinline__ void ld_b(short8 (&b)[2][2], const char* lds, int brow, int c0, int c1) {
    #pragma unroll
    for (int nf = 0; nf < 2; ++nf) {
        b[nf][0] = *(const short8*)(lds + ROFF + QH * 16384 + nf * 2048 + brow + c0);
        b[nf][1] = *(const short8*)(lds + ROFF + QH * 16384 + nf * 2048 + brow + c1);
    }
}

template<int QM, int QN>
__device__ __forceinline__ void mfq(f32x4 (&acc)[2][4][2][2], short8 (&a)[4][2], short8 (&b)[2][2]) {
    __builtin_amdgcn_s_setprio(1);
    #pragma unroll
    for (int mf = 0; mf < 4; ++mf)
        #pragma unroll
        for (int nf = 0; nf < 2; ++nf) {
            acc[QM][mf][QN][nf] = __builtin_amdgcn_mfma_f32_16x16x32_bf16(a[mf][0], b[nf][0], acc[QM][mf][QN][nf], 0, 0, 0);
            acc[QM][mf][QN][nf] = __builtin_amdgcn_mfma_f32_16x16x32_bf16(a[mf][1], b[nf][1], acc[QM][mf][QN][nf], 0, 0, 0);
        }
    __builtin_amdgcn_s_setprio(0);
}

// ---------------------------------------------------------------------------
// 256x256 8-phase bf16 GEMM — R10/R12 schedule, fence-only barriers.
// A [M][K] rm, B [N][K] rm. Snake Q00->Q01->Q11->Q10 per K-tile; B halves in regs.
// Stage slots: ph1: buf1.Ah1[T+1]  ph3: buf0.Bh0[T+2]  ph4: buf0.Bh1 ;gate(4)
//   ph5: buf0.Ah0  ph6: buf0.Ah1  ph7: buf1.Bh0+Bh1[T+3]  ph8: buf1.Ah0 ;gate(6)
// WAR ledger holds under fence-only semantics: every stage target's last
// reader drains (lgkm wait before its mfq) >= one barrier before stage issue.
// LDS 128 KiB: buf0A@0 buf0B@32768 buf1A@65536 buf1B@98304, [256][64] each,
// 16B-slot swizzle: LDS[row][s] = G[row][s ^ (row&7)].
// EPI: 0 = QKV: cols<2048 -> bf16 qkv + bias ; cols>=2048 -> V transposed to vt
//      3 = bf16 out = exp(acc*scale), row-sums -> ps[(z*2048+row)*GX+bx] (QKT)
//      4 = f32 out = acc * (1/sum(ps[row][0..7]))  (PV; dinv computed in-block)
// ---------------------------------------------------------------------------
template<int EPI, int LDA, int LDB, int LDC, int K>
__global__ __launch_bounds__(512, 2)
void gemm8p(const u16* __restrict__ A, long long sA,
            const u16* __restrict__ B, long long sB,
            void* __restrict__ Cv, long long sC,
            const float* __restrict__ bias, float* __restrict__ ps,
            u16* __restrict__ vt, float scale, int GX, int GY)
{
    extern __shared__ char lds[];
    const int tid  = threadIdx.x;
    const int wid  = tid >> 6;
    const int lane = tid & 63;

    // bijective XCD swizzle (all grids are multiples of 8)
    const int nwg = gridDim.x;
    int bid = blockIdx.x;
    bid = (bid & 7) * (nwg >> 3) + (bid >> 3);
    const int bx  = bid % GX;
    const int rem = bid / GX;
    const int by  = rem % GY;
    const long long z = rem / GY;

    const int bm = by * 256, bn = bx * 256;
    const u16* Atile = A + z * sA + (size_t)bm * LDA;
    const u16* Btile = B + z * sB + (size_t)bn * LDB;

    const int wm = wid >> 2, wn = wid & 3;
    const int l15   = lane & 15;
    const int lxor  = (lane & 7) << 4;
    const int khi   = (lane >> 4) << 4;
    const int colk0 = khi ^ lxor;
    const int colk1 = (64 + khi) ^ lxor;
    const int arow  = (wm * 64 + l15) * 128;
    const int brow  = (wn * 32 + l15) * 128;

    const int swz = ((lane & 7) ^ (lane >> 3)) << 3;   // inverse-swizzled src col (elems)
    const u16* pA = Atile + (size_t)((wid << 3) + (lane >> 3)) * LDA + swz;
    const u16* pB = Btile + (size_t)((wid << 3) + (lane >> 3)) * LDB + swz;

    f32x4 acc[2][4][2][2];
    #pragma unroll
    for (int i = 0; i < 2; ++i)
        #pragma unroll
        for (int m = 0; m < 4; ++m)
            #pragma unroll
            for (int j = 0; j < 2; ++j)
                #pragma unroll
                for (int n = 0; n < 2; ++n)
                    acc[i][m][j][n] = (f32x4){0.f, 0.f, 0.f, 0.f};

    // prologue: buf0 <- T0 (8 loads), buf1 <- T1 {Ah0, Bh0, Bh1} (6 loads)
    STAGE(pA, LDA, 0,     0,   0);  STAGE(pA, LDA, 0,     128, 0);
    STAGE(pB, LDB, 32768, 0,   0);  STAGE(pB, LDB, 32768, 128, 0);
    STAGE(pA, LDA, 65536, 0,   64);
    STAGE(pB, LDB, 98304, 0,   64); STAGE(pB, LDB, 98304, 128, 64);
    VMCNT(6);
    BARRIER();

    short8 a[4][2], b0[2][2], b1[2][2];
    const int NI = K >> 7;     // two 64-wide K-tiles per iteration

    for (int it = 0; it < NI; ++it) {
        const bool more = (it + 1 < NI);
        const int kc1 = it * 128 + 64;     // current pair's 2nd tile (buf1)
        const int kn  = it * 128 + 128;    // T+2 (-> buf0)
        const int kn2 = kn + 64;           // T+3 (-> buf1)

        // ph1: Q00 buf0 ; stage buf1.Ah1 (completes T+1)
        ld_a<0, 0>(a, lds, arow, colk0, colk1);
        ld_b<32768, 0>(b0, lds, brow, colk0, colk1);
        STAGE(pA, LDA, 65536, 128, kc1);
        BARRIER(); mfq<0, 0>(acc, a, b0);
        // ph2: Q01 buf0
        ld_b<32768, 1>(b1, lds, brow, colk0, colk1);
        BARRIER(); mfq<0, 1>(acc, a, b1);
        // ph3: Q11 buf0 ; stage buf0.Bh0 <- T+2
        ld_a<0, 1>(a, lds, arow, colk0, colk1);
        if (more) STAGE(pB, LDB, 32768, 0, kn);
        BARRIER(); mfq<1, 1>(acc, a, b1);
        // ph4: Q10 buf0 ; stage buf0.Bh1 <- T+2 ; end-gate buf1(T+1)
        if (more) { STAGE(pB, LDB, 32768, 128, kn); VMCNT(4); }
        else      { VMCNT(0); }
        BARRIER(); mfq<1, 0>(acc, a, b0);
        // ph5: Q00 buf1 ; stage buf0.Ah0 <- T+2
        ld_a<65536, 0>(a, lds, arow, colk0, colk1);
        ld_b<98304, 0>(b0, lds, brow, colk0, colk1);
        if (more) STAGE(pA, LDA, 0, 0, kn);
        BARRIER(); mfq<0, 0>(acc, a, b0);
        // ph6: Q01 buf1 ; stage buf0.Ah1 <- T+2
        ld_b<98304, 1>(b1, lds, brow, colk0, colk1);
        if (more) STAGE(pA, LDA, 0, 128, kn);
        BARRIER(); mfq<0, 1>(acc, a, b1);
        // ph7: Q11 buf1 ; stage buf1.Bh0+Bh1 <- T+3
        ld_a<65536, 1>(a, lds, arow, colk0, colk1);
        if (more) { STAGE(pB, LDB, 98304, 0, kn2); STAGE(pB, LDB, 98304, 128, kn2); }
        BARRIER(); mfq<1, 1>(acc, a, b1);
        // ph8: Q10 buf1 ; stage buf1.Ah0 <- T+3 ; end-gate buf0(T+2)
        if (more) STAGE(pA, LDA, 65536, 0, kn2);
        VMCNT(6);                          // no-op on final iter (queue empty)
        BARRIER(); mfq<1, 0>(acc, a, b0);
    }

    // epilogue. C/D map (m89): col = lane&15, row = 4*(lane>>4)+reg
    const int r0 = (lane >> 4) * 4;
    const int cc = lane & 15;

    if (EPI == 3) {
        BARRIER();                       // all waves done with buf LDS -> reuse
        float* rs = (float*)lds;         // [4][256]
        u16* C = (u16*)Cv + z * sC;
        float rsum[2][4][4];
        #pragma unroll
        for (int qm = 0; qm < 2; ++qm)
            #pragma unroll
            for (int mf = 0; mf < 4; ++mf)
                #pragma unroll
                for (int r = 0; r < 4; ++r) rsum[qm][mf][r] = 0.f;
        #pragma unroll
        for (int qn = 0; qn < 2; ++qn)
            #pragma unroll
            for (int nf = 0; nf < 2; ++nf) {
                const int col = bn + qn * 128 + wn * 32 + nf * 16 + cc;
                #pragma unroll
                for (int qm = 0; qm < 2; ++qm)
                    #pragma unroll
                    for (int mf = 0; mf < 4; ++mf) {
                        const int row = bm + qm * 128 + wm * 64 + mf * 16 + r0;
                        #pragma unroll
                        for (int r = 0; r < 4; ++r) {
                            const float e = __expf(acc[qm][mf][qn][nf][r] * scale);
                            const u16 eb = f2bf(e);
                            C[(size_t)(row + r) * LDC + col] = eb;
                            rsum[qm][mf][r] += bf2f(eb);
                        }
                    }
            }
        #pragma unroll
        for (int qm = 0; qm < 2; ++qm)
            #pragma unroll
            for (int mf = 0; mf < 4; ++mf)
                #pragma unroll
                for (int r = 0; r < 4; ++r) {
                    float v = rsum[qm][mf][r];
                    v += __shfl_xor(v, 1); v += __shfl_xor(v, 2);
                    v += __shfl_xor(v, 4); v += __shfl_xor(v, 8);
                    if (cc == 0)
                        rs[wn * 256 + qm * 128 + wm * 64 + mf * 16 + r0 + r] = v;
                }
        __syncthreads();
        if (tid < 256) {
            const float s = rs[tid] + rs[256 + tid] + rs[512 + tid] + rs[768 + tid];
            ps[((size_t)z * 2048 + bm + tid) * GX + bx] = s;
        }
        return;
    }

    if (EPI == 4) {
        // per-block softmax denominators from ps[row][0..7] -> LDS
        BARRIER();                       // all waves done with buf LDS -> reuse
        float* di = (float*)lds;         // [256]
        if (tid < 256) {
            const float* p = ps + ((size_t)z * 2048 + bm + tid) * 8;
            const float s = ((p[0] + p[1]) + (p[2] + p[3])) + ((p[4] + p[5]) + (p[6] + p[7]));
            di[tid] = 1.0f / s;
        }
        __syncthreads();
        float* C = (float*)Cv + z * sC;
        #pragma unroll
        for (int qn = 0; qn < 2; ++qn)
            #pragma unroll
            for (int nf = 0; nf < 2; ++nf) {
                const int col = bn + qn * 128 + wn * 32 + nf * 16 + cc;
                #pragma unroll
                for (int qm = 0; qm < 2; ++qm)
                    #pragma unroll
                    for (int mf = 0; mf < 4; ++mf) {
                        const int ro = qm * 128 + wm * 64 + mf * 16 + r0;
                        #pragma unroll
                        for (int r = 0; r < 4; ++r)
                            C[(size_t)(bm + ro + r) * LDC + col] = acc[qm][mf][qn][nf][r] * di[ro + r];
                    }
            }
        return;
    }

    if (EPI == 0 && bn >= 2048) {
        // V block: write transposed straight into Vt [B][1024][2048]
        #pragma unroll
        for (int qn = 0; qn < 2; ++qn)
            #pragma unroll
            for (int nf = 0; nf < 2; ++nf) {
                const int col = bn + qn * 128 + wn * 32 + nf * 16 + cc;
                const float badd = bias[col];
                const int e = col - 2048;
                #pragma unroll
                for (int qm = 0; qm < 2; ++qm)
                    #pragma unroll
                    for (int mf = 0; mf < 4; ++mf) {
                        const int row = bm + qm * 128 + wm * 64 + mf * 16 + r0;
                        short4v o;
                        #pragma unroll
                        for (int r = 0; r < 4; ++r)
                            o[r] = (short)f2bf(acc[qm][mf][qn][nf][r] + badd);
                        *(short4v*)&vt[((size_t)(row >> 11) << 21) + (size_t)e * 2048 + (row & 2047)] = o;
                    }
            }
        return;
    }

    // EPI == 0, Q/K columns
    #pragma unroll
    for (int qn = 0; qn < 2; ++qn)
        #pragma unroll
        for (int nf = 0; nf < 2; ++nf) {
            const int col = bn + qn * 128 + wn * 32 + nf * 16 + cc;
            const float badd = bias[col];
            #pragma unroll
            for (int qm = 0; qm < 2; ++qm)
                #pragma unroll
                for (int mf = 0; mf < 4; ++mf) {
                    const int row = bm + qm * 128 + wm * 64 + mf * 16 + r0;
                    #pragma unroll
                    for (int r = 0; r < 4; ++r) {
                        const float v = acc[qm][mf][qn][nf][r] + badd;
                        ((u16*)Cv + z * sC)[(size_t)(row + r) * LDC + col] = f2bf(v);
                    }
                }
        }
}

// ---------------------------------------------------------------------------
// fused input prep: blocks [0,2048) convert x f32->bf16 (grid-stride, 32B/iter);
// blocks [2048,5120) transpose-convert W [1024][3072] -> Wt [3072][1024]
__global__ __launch_bounds__(256)
void cvt_fused(const float* __restrict__ x, u16* __restrict__ xb,
               const float* __restrict__ W, u16* __restrict__ Wt)
{
    __shared__ u16 T[32][33];
    const int blk = blockIdx.x;
    const int tid = threadIdx.x;
    if (blk < 2048) {
        const float4* p = (const float4*)x;
        #pragma unroll
        for (int itr = 0; itr < 4; ++itr) {
            const int i = blk * 256 + tid + itr * 524288;
            const float4 a = p[2 * i], b = p[2 * i + 1];
            short8 o;
            o[0] = (short)f2bf(a.x); o[1] = (short)f2bf(a.y);
            o[2] = (short)f2bf(a.z); o[3] = (short)f2bf(a.w);
            o[4] = (short)f2bf(b.x); o[5] = (short)f2bf(b.y);
            o[6] = (short)f2bf(b.z); o[7] = (short)f2bf(b.w);
            ((short8*)xb)[i] = o;
        }
        return;
    }
    const int wb = blk - 2048;
    const int c0 = (wb % 96) * 32;
    const int r0 = (wb / 96) * 32;
    const int tr = tid >> 3;
    const int tc = (tid & 7) * 4;
    const float4 v = *(const float4*)&W[(size_t)(r0 + tr) * 3072 + c0 + tc];
    T[tr][tc + 0] = f2bf(v.x); T[tr][tc + 1] = f2bf(v.y);
    T[tr][tc + 2] = f2bf(v.z); T[tr][tc + 3] = f2bf(v.w);
    __syncthreads();
    short4v o;
    o[0] = (short)T[tc + 0][tr]; o[1] = (short)T[tc + 1][tr];
    o[2] = (short)T[tc + 2][tr]; o[3] = (short)T[tc + 3][tr];
    *(short4v*)&Wt[(size_t)(c0 + tr) * 1024 + r0 + tc] = o;
}

// ---------------------------------------------------------------------------
extern "C" void kernel_launch(void* const* d_in, const int* in_sizes, int n_in,
                              void* d_out, int out_size, void* d_ws, size_t ws_size,
                              hipStream_t stream) {
    const float* x    = (const float*)d_in[0];   // [8,2048,1024]
    const float* W    = (const float*)d_in[1];   // [1024,3072]
    const float* bias = (const float*)d_in[2];   // [3072]
    float* out = (float*)d_out;                  // [8,2048,1024] f32

    const int B = 8, S = 2048, E = 1024, N3 = 3072;
    const int M = B * S;                         // 16384

    char* ws = (char*)d_ws;
    u16* xb   = (u16*)ws;                          // 32 MiB  [M][E]
    u16* Wtb  = (u16*)(ws + 33554432);             //  6 MiB  [3072][1024]
    u16* qkvb = (u16*)(ws + 39845888);             // 96 MiB  [M][3072] (Q,K thirds used)
    u16* Vtb  = (u16*)(ws + 140509184);            // 32 MiB  [B][1024][2048]
    u16* Sb   = (u16*)(ws + 174063616);            // E=exp scores

    const size_t sbFull = (size_t)B * S * S * 2;          // 64 MiB
    const size_t sbOne  = (size_t)S * S * 2;              //  8 MiB
    const size_t psFull = (size_t)M * 8 * sizeof(float);  // 512 KiB
    const size_t need_full = 174063616ull + sbFull + psFull;
    const bool full = ws_size >= need_full;

    float* Ps = (float*)(ws + 174063616 + (full ? sbFull : sbOne));

    const float sc = 1.0f / 32.0f;
    const int LDSB = 131072;

    // instantiations: <EPI, LDA, LDB, LDC, K>
    auto kQKV = gemm8p<0, 1024, 1024, 3072, 1024>;
    auto kQKT = gemm8p<3, 3072, 3072, 2048, 1024>;
    auto kPV  = gemm8p<4, 2048, 2048, 1024, 2048>;
    (void)hipFuncSetAttribute(reinterpret_cast<const void*>(kQKV),
                              hipFuncAttributeMaxDynamicSharedMemorySize, LDSB);
    (void)hipFuncSetAttribute(reinterpret_cast<const void*>(kQKT),
                              hipFuncAttributeMaxDynamicSharedMemorySize, LDSB);
    (void)hipFuncSetAttribute(reinterpret_cast<const void*>(kPV),
                              hipFuncAttributeMaxDynamicSharedMemorySize, LDSB);

    // fused x-convert + W-transpose
    cvt_fused<<<dim3(5120), 256, 0, stream>>>(x, xb, W, Wtb);

    // qkv = x @ W + b : grid 12 x 64 ; V third written transposed into Vtb
    kQKV<<<dim3(12 * 64), 512, LDSB, stream>>>(xb, 0, Wtb, 0, qkvb, 0,
                                               bias, nullptr, Vtb, 1.0f, 12, 64);

    if (full) {
        // Sb = exp(Q K^T * sc), row sums -> Ps
        kQKT<<<dim3(8 * 8 * 8), 512, LDSB, stream>>>(
            qkvb, (long long)S * N3, qkvb + E, (long long)S * N3,
            Sb, (long long)S * S, nullptr, Ps, nullptr, sc, 8, 8);
        // out = (Sb @ Vt^T) * (1/rowsum)  — denominators folded into epilogue
        kPV<<<dim3(4 * 8 * 8), 512, LDSB, stream>>>(
            Sb, (long long)S * S, Vtb, (long long)E * S,
            out, (long long)S * E, nullptr, Ps, nullptr, 1.0f, 4, 8);
    } else {
        for (int b = 0; b < B; ++b) {
            const u16* Qb = qkvb + (size_t)b * S * N3;
            kQKT<<<dim3(8 * 8), 512, LDSB, stream>>>(
                Qb, 0, Qb + E, 0, Sb, 0, nullptr, Ps, nullptr, sc, 8, 8);
            kPV<<<dim3(4 * 8), 512, LDSB, stream>>>(
                Sb, 0, Vtb + (size_t)b * E * S, 0,
                out + (size_t)b * S * E, 0, nullptr, Ps, nullptr, 1.0f, 4, 8);
        }
    }
}

// Round 14
// 267.963 us; speedup vs baseline: 1.2825x; 1.2825x over previous
//
#include <hip/hip_runtime.h>

typedef unsigned short u16;
typedef unsigned int u32;
typedef __attribute__((ext_vector_type(8))) short short8;
typedef __attribute__((ext_vector_type(4))) short short4v;
typedef __attribute__((ext_vector_type(4))) float f32x4;

__device__ __forceinline__ u16 f2bf(float f) {
    u32 u = __float_as_uint(f);
    u32 r = (u + 0x7fffu + ((u >> 16) & 1u)) >> 16;   // RNE
    return (u16)r;
}
__device__ __forceinline__ float bf2f(u16 h) {
    return __uint_as_float(((u32)h) << 16);
}

__device__ __forceinline__ void gload_lds16(const void* g, void* l) {
    __builtin_amdgcn_global_load_lds((const __attribute__((address_space(1))) void*)g,
                                     (__attribute__((address_space(3))) void*)l, 16, 0, 0);
}

// pinned barrier: sched_barrier(0) walls are LOAD-BEARING (R13 A/B: removing
// them regressed GEMMs 105->141 us; compiler reordering breaks the phase
// discipline). Do not relax.
#define BARRIER() do { __builtin_amdgcn_sched_barrier(0); __builtin_amdgcn_s_barrier(); __builtin_amdgcn_sched_barrier(0); } while (0)
#define VMCNT(N)  asm volatile("s_waitcnt vmcnt(" #N ")" ::: "memory")

// stage one 128-row half (2 global_load_lds per thread; dest linear, src inverse-swizzled)
#define STAGE(ptr, LDG, LOFF, RBASE, kelem) \
    do { gload_lds16((ptr) + (size_t)(RBASE) * (LDG) + (kelem),        lds + (LOFF) + ((RBASE) + (wid << 3)) * 128); \
         gload_lds16((ptr) + (size_t)((RBASE) + 64) * (LDG) + (kelem), lds + (LOFF) + ((RBASE) + 64 + (wid << 3)) * 128); } while (0)

template<int ROFF, int QH>
__device__ __forceinline__ void ld_a(short8 (&a)[4][2], const char* lds, int arow, int c0, int c1) {
    #pragma unroll
    for (int mf = 0; mf < 4; ++mf) {
        a[mf][0] = *(const short8*)(lds + ROFF + QH * 16384 + mf * 2048 + arow + c0);
        a[mf][1] = *(const short8*)(lds + ROFF + QH * 16384 + mf * 2048 + arow + c1);
    }
}
template<int ROFF, int QH>
__device__ __forceinline__ void ld_b(short8 (&b)[2][2], const char* lds, int brow, int c0, int c1) {
    #pragma unroll
    for (int nf = 0; nf < 2; ++nf) {
        b[nf][0] = *(const short8*)(lds + ROFF + QH * 16384 + nf * 2048 + brow + c0);
        b[nf][1] = *(const short8*)(lds + ROFF + QH * 16384 + nf * 2048 + brow + c1);
    }
}

template<int QM, int QN>
__device__ __forceinline__ void mfq(f32x4 (&acc)[2][4][2][2], short8 (&a)[4][2], short8 (&b)[2][2]) {
    __builtin_amdgcn_s_setprio(1);
    #pragma unroll
    for (int mf = 0; mf < 4; ++mf)
        #pragma unroll
        for (int nf = 0; nf < 2; ++nf) {
            acc[QM][mf][QN][nf] = __builtin_amdgcn_mfma_f32_16x16x32_bf16(a[mf][0], b[nf][0], acc[QM][mf][QN][nf], 0, 0, 0);
            acc[QM][mf][QN][nf] = __builtin_amdgcn_mfma_f32_16x16x32_bf16(a[mf][1], b[nf][1], acc[QM][mf][QN][nf], 0, 0, 0);
        }
    __builtin_amdgcn_s_setprio(0);
}

// ---------------------------------------------------------------------------
// 256x256 8-phase bf16 GEMM — best measured configuration (R12, 260.2 us).
// A [M][K] rm, B [N][K] rm. Snake Q00->Q01->Q11->Q10 per K-tile; B halves in regs.
// Stage slots: ph1: buf1.Ah1[T+1]  ph3: buf0.Bh0[T+2]  ph4: buf0.Bh1 ;gate(4)
//   ph5: buf0.Ah0  ph6: buf0.Ah1  ph7: buf1.Bh0+Bh1[T+3]  ph8: buf1.Ah0 ;gate(6)
// Gates at end of phase, published by that phase's barrier (FIFO-verified).
// LDS 128 KiB: buf0A@0 buf0B@32768 buf1A@65536 buf1B@98304, [256][64] each,
// 16B-slot swizzle: LDS[row][s] = G[row][s ^ (row&7)].
// EPI: 0 = QKV: cols<2048 -> bf16 qkv + bias ; cols>=2048 -> V transposed to vt
//      3 = bf16 out = exp(acc*scale), row-sums -> ps[(z*2048+row)*GX+bx] (QKT)
//      4 = f32 out = acc * (1/sum(ps[row][0..7]))  (PV; dinv computed in-block)
// ---------------------------------------------------------------------------
template<int EPI, int LDA, int LDB, int LDC, int K>
__global__ __launch_bounds__(512, 2)
void gemm8p(const u16* __restrict__ A, long long sA,
            const u16* __restrict__ B, long long sB,
            void* __restrict__ Cv, long long sC,
            const float* __restrict__ bias, float* __restrict__ ps,
            u16* __restrict__ vt, float scale, int GX, int GY)
{
    extern __shared__ char lds[];
    const int tid  = threadIdx.x;
    const int wid  = tid >> 6;
    const int lane = tid & 63;

    // bijective XCD swizzle (all grids are multiples of 8)
    const int nwg = gridDim.x;
    int bid = blockIdx.x;
    bid = (bid & 7) * (nwg >> 3) + (bid >> 3);
    const int bx  = bid % GX;
    const int rem = bid / GX;
    const int by  = rem % GY;
    const long long z = rem / GY;

    const int bm = by * 256, bn = bx * 256;
    const u16* Atile = A + z * sA + (size_t)bm * LDA;
    const u16* Btile = B + z * sB + (size_t)bn * LDB;

    const int wm = wid >> 2, wn = wid & 3;
    const int l15   = lane & 15;
    const int lxor  = (lane & 7) << 4;
    const int khi   = (lane >> 4) << 4;
    const int colk0 = khi ^ lxor;
    const int colk1 = (64 + khi) ^ lxor;
    const int arow  = (wm * 64 + l15) * 128;
    const int brow  = (wn * 32 + l15) * 128;

    const int swz = ((lane & 7) ^ (lane >> 3)) << 3;   // inverse-swizzled src col (elems)
    const u16* pA = Atile + (size_t)((wid << 3) + (lane >> 3)) * LDA + swz;
    const u16* pB = Btile + (size_t)((wid << 3) + (lane >> 3)) * LDB + swz;

    f32x4 acc[2][4][2][2];
    #pragma unroll
    for (int i = 0; i < 2; ++i)
        #pragma unroll
        for (int m = 0; m < 4; ++m)
            #pragma unroll
            for (int j = 0; j < 2; ++j)
                #pragma unroll
                for (int n = 0; n < 2; ++n)
                    acc[i][m][j][n] = (f32x4){0.f, 0.f, 0.f, 0.f};

    // prologue: buf0 <- T0 (8 loads), buf1 <- T1 {Ah0, Bh0, Bh1} (6 loads)
    STAGE(pA, LDA, 0,     0,   0);  STAGE(pA, LDA, 0,     128, 0);
    STAGE(pB, LDB, 32768, 0,   0);  STAGE(pB, LDB, 32768, 128, 0);
    STAGE(pA, LDA, 65536, 0,   64);
    STAGE(pB, LDB, 98304, 0,   64); STAGE(pB, LDB, 98304, 128, 64);
    VMCNT(6);
    BARRIER();

    short8 a[4][2], b0[2][2], b1[2][2];
    const int NI = K >> 7;     // two 64-wide K-tiles per iteration

    for (int it = 0; it < NI; ++it) {
        const bool more = (it + 1 < NI);
        const int kc1 = it * 128 + 64;     // current pair's 2nd tile (buf1)
        const int kn  = it * 128 + 128;    // T+2 (-> buf0)
        const int kn2 = kn + 64;           // T+3 (-> buf1)

        // ph1: Q00 buf0 ; stage buf1.Ah1 (completes T+1)
        ld_a<0, 0>(a, lds, arow, colk0, colk1);
        ld_b<32768, 0>(b0, lds, brow, colk0, colk1);
        STAGE(pA, LDA, 65536, 128, kc1);
        BARRIER(); mfq<0, 0>(acc, a, b0);
        // ph2: Q01 buf0
        ld_b<32768, 1>(b1, lds, brow, colk0, colk1);
        BARRIER(); mfq<0, 1>(acc, a, b1);
        // ph3: Q11 buf0 ; stage buf0.Bh0 <- T+2
        ld_a<0, 1>(a, lds, arow, colk0, colk1);
        if (more) STAGE(pB, LDB, 32768, 0, kn);
        BARRIER(); mfq<1, 1>(acc, a, b1);
        // ph4: Q10 buf0 ; stage buf0.Bh1 <- T+2 ; end-gate buf1(T+1)
        if (more) { STAGE(pB, LDB, 32768, 128, kn); VMCNT(4); }
        else      { VMCNT(0); }
        BARRIER(); mfq<1, 0>(acc, a, b0);
        // ph5: Q00 buf1 ; stage buf0.Ah0 <- T+2
        ld_a<65536, 0>(a, lds, arow, colk0, colk1);
        ld_b<98304, 0>(b0, lds, brow, colk0, colk1);
        if (more) STAGE(pA, LDA, 0, 0, kn);
        BARRIER(); mfq<0, 0>(acc, a, b0);
        // ph6: Q01 buf1 ; stage buf0.Ah1 <- T+2
        ld_b<98304, 1>(b1, lds, brow, colk0, colk1);
        if (more) STAGE(pA, LDA, 0, 128, kn);
        BARRIER(); mfq<0, 1>(acc, a, b1);
        // ph7: Q11 buf1 ; stage buf1.Bh0+Bh1 <- T+3
        ld_a<65536, 1>(a, lds, arow, colk0, colk1);
        if (more) { STAGE(pB, LDB, 98304, 0, kn2); STAGE(pB, LDB, 98304, 128, kn2); }
        BARRIER(); mfq<1, 1>(acc, a, b1);
        // ph8: Q10 buf1 ; stage buf1.Ah0 <- T+3 ; end-gate buf0(T+2)
        if (more) STAGE(pA, LDA, 65536, 0, kn2);
        VMCNT(6);                          // no-op on final iter (queue empty)
        BARRIER(); mfq<1, 0>(acc, a, b0);
    }

    // epilogue. C/D map (m89): col = lane&15, row = 4*(lane>>4)+reg
    const int r0 = (lane >> 4) * 4;
    const int cc = lane & 15;

    if (EPI == 3) {
        BARRIER();                       // all waves done with buf LDS -> reuse
        float* rs = (float*)lds;         // [4][256]
        u16* C = (u16*)Cv + z * sC;
        float rsum[2][4][4];
        #pragma unroll
        for (int qm = 0; qm < 2; ++qm)
            #pragma unroll
            for (int mf = 0; mf < 4; ++mf)
                #pragma unroll
                for (int r = 0; r < 4; ++r) rsum[qm][mf][r] = 0.f;
        #pragma unroll
        for (int qn = 0; qn < 2; ++qn)
            #pragma unroll
            for (int nf = 0; nf < 2; ++nf) {
                const int col = bn + qn * 128 + wn * 32 + nf * 16 + cc;
                #pragma unroll
                for (int qm = 0; qm < 2; ++qm)
                    #pragma unroll
                    for (int mf = 0; mf < 4; ++mf) {
                        const int row = bm + qm * 128 + wm * 64 + mf * 16 + r0;
                        #pragma unroll
                        for (int r = 0; r < 4; ++r) {
                            const float e = __expf(acc[qm][mf][qn][nf][r] * scale);
                            const u16 eb = f2bf(e);
                            C[(size_t)(row + r) * LDC + col] = eb;
                            rsum[qm][mf][r] += bf2f(eb);
                        }
                    }
            }
        #pragma unroll
        for (int qm = 0; qm < 2; ++qm)
            #pragma unroll
            for (int mf = 0; mf < 4; ++mf)
                #pragma unroll
                for (int r = 0; r < 4; ++r) {
                    float v = rsum[qm][mf][r];
                    v += __shfl_xor(v, 1); v += __shfl_xor(v, 2);
                    v += __shfl_xor(v, 4); v += __shfl_xor(v, 8);
                    if (cc == 0)
                        rs[wn * 256 + qm * 128 + wm * 64 + mf * 16 + r0 + r] = v;
                }
        __syncthreads();
        if (tid < 256) {
            const float s = rs[tid] + rs[256 + tid] + rs[512 + tid] + rs[768 + tid];
            ps[((size_t)z * 2048 + bm + tid) * GX + bx] = s;
        }
        return;
    }

    if (EPI == 4) {
        // per-block softmax denominators from ps[row][0..7] -> LDS
        BARRIER();                       // all waves done with buf LDS -> reuse
        float* di = (float*)lds;         // [256]
        if (tid < 256) {
            const float* p = ps + ((size_t)z * 2048 + bm + tid) * 8;
            const float s = ((p[0] + p[1]) + (p[2] + p[3])) + ((p[4] + p[5]) + (p[6] + p[7]));
            di[tid] = 1.0f / s;
        }
        __syncthreads();
        float* C = (float*)Cv + z * sC;
        #pragma unroll
        for (int qn = 0; qn < 2; ++qn)
            #pragma unroll
            for (int nf = 0; nf < 2; ++nf) {
                const int col = bn + qn * 128 + wn * 32 + nf * 16 + cc;
                #pragma unroll
                for (int qm = 0; qm < 2; ++qm)
                    #pragma unroll
                    for (int mf = 0; mf < 4; ++mf) {
                        const int ro = qm * 128 + wm * 64 + mf * 16 + r0;
                        #pragma unroll
                        for (int r = 0; r < 4; ++r)
                            C[(size_t)(bm + ro + r) * LDC + col] = acc[qm][mf][qn][nf][r] * di[ro + r];
                    }
            }
        return;
    }

    if (EPI == 0 && bn >= 2048) {
        // V block: write transposed straight into Vt [B][1024][2048]
        #pragma unroll
        for (int qn = 0; qn < 2; ++qn)
            #pragma unroll
            for (int nf = 0; nf < 2; ++nf) {
                const int col = bn + qn * 128 + wn * 32 + nf * 16 + cc;
                const float badd = bias[col];
                const int e = col - 2048;
                #pragma unroll
                for (int qm = 0; qm < 2; ++qm)
                    #pragma unroll
                    for (int mf = 0; mf < 4; ++mf) {
                        const int row = bm + qm * 128 + wm * 64 + mf * 16 + r0;
                        short4v o;
                        #pragma unroll
                        for (int r = 0; r < 4; ++r)
                            o[r] = (short)f2bf(acc[qm][mf][qn][nf][r] + badd);
                        *(short4v*)&vt[((size_t)(row >> 11) << 21) + (size_t)e * 2048 + (row & 2047)] = o;
                    }
            }
        return;
    }

    // EPI == 0, Q/K columns
    #pragma unroll
    for (int qn = 0; qn < 2; ++qn)
        #pragma unroll
        for (int nf = 0; nf < 2; ++nf) {
            const int col = bn + qn * 128 + wn * 32 + nf * 16 + cc;
            const float badd = bias[col];
            #pragma unroll
            for (int qm = 0; qm < 2; ++qm)
                #pragma unroll
                for (int mf = 0; mf < 4; ++mf) {
                    const int row = bm + qm * 128 + wm * 64 + mf * 16 + r0;
                    #pragma unroll
                    for (int r = 0; r < 4; ++r) {
                        const float v = acc[qm][mf][qn][nf][r] + badd;
                        ((u16*)Cv + z * sC)[(size_t)(row + r) * LDC + col] = f2bf(v);
                    }
                }
        }
}

// ---------------------------------------------------------------------------
// fused input prep: blocks [0,2048) convert x f32->bf16 (grid-stride, 32B/iter);
// blocks [2048,5120) transpose-convert W [1024][3072] -> Wt [3072][1024]
__global__ __launch_bounds__(256)
void cvt_fused(const float* __restrict__ x, u16* __restrict__ xb,
               const float* __restrict__ W, u16* __restrict__ Wt)
{
    __shared__ u16 T[32][33];
    const int blk = blockIdx.x;
    const int tid = threadIdx.x;
    if (blk < 2048) {
        const float4* p = (const float4*)x;
        #pragma unroll
        for (int itr = 0; itr < 4; ++itr) {
            const int i = blk * 256 + tid + itr * 524288;
            const float4 a = p[2 * i], b = p[2 * i + 1];
            short8 o;
            o[0] = (short)f2bf(a.x); o[1] = (short)f2bf(a.y);
            o[2] = (short)f2bf(a.z); o[3] = (short)f2bf(a.w);
            o[4] = (short)f2bf(b.x); o[5] = (short)f2bf(b.y);
            o[6] = (short)f2bf(b.z); o[7] = (short)f2bf(b.w);
            ((short8*)xb)[i] = o;
        }
        return;
    }
    const int wb = blk - 2048;
    const int c0 = (wb % 96) * 32;
    const int r0 = (wb / 96) * 32;
    const int tr = tid >> 3;
    const int tc = (tid & 7) * 4;
    const float4 v = *(const float4*)&W[(size_t)(r0 + tr) * 3072 + c0 + tc];
    T[tr][tc + 0] = f2bf(v.x); T[tr][tc + 1] = f2bf(v.y);
    T[tr][tc + 2] = f2bf(v.z); T[tr][tc + 3] = f2bf(v.w);
    __syncthreads();
    short4v o;
    o[0] = (short)T[tc + 0][tr]; o[1] = (short)T[tc + 1][tr];
    o[2] = (short)T[tc + 2][tr]; o[3] = (short)T[tc + 3][tr];
    *(short4v*)&Wt[(size_t)(c0 + tr) * 1024 + r0 + tc] = o;
}

// ---------------------------------------------------------------------------
extern "C" void kernel_launch(void* const* d_in, const int* in_sizes, int n_in,
                              void* d_out, int out_size, void* d_ws, size_t ws_size,
                              hipStream_t stream) {
    const float* x    = (const float*)d_in[0];   // [8,2048,1024]
    const float* W    = (const float*)d_in[1];   // [1024,3072]
    const float* bias = (const float*)d_in[2];   // [3072]
    float* out = (float*)d_out;                  // [8,2048,1024] f32

    const int B = 8, S = 2048, E = 1024, N3 = 3072;
    const int M = B * S;                         // 16384

    char* ws = (char*)d_ws;
    u16* xb   = (u16*)ws;                          // 32 MiB  [M][E]
    u16* Wtb  = (u16*)(ws + 33554432);             //  6 MiB  [3072][1024]
    u16* qkvb = (u16*)(ws + 39845888);             // 96 MiB  [M][3072] (Q,K thirds used)
    u16* Vtb  = (u16*)(ws + 140509184);            // 32 MiB  [B][1024][2048]
    u16* Sb   = (u16*)(ws + 174063616);            // E=exp scores

    const size_t sbFull = (size_t)B * S * S * 2;          // 64 MiB
    const size_t sbOne  = (size_t)S * S * 2;              //  8 MiB
    const size_t psFull = (size_t)M * 8 * sizeof(float);  // 512 KiB
    const size_t need_full = 174063616ull + sbFull + psFull;
    const bool full = ws_size >= need_full;

    float* Ps = (float*)(ws + 174063616 + (full ? sbFull : sbOne));

    const float sc = 1.0f / 32.0f;
    const int LDSB = 131072;

    // instantiations: <EPI, LDA, LDB, LDC, K>
    auto kQKV = gemm8p<0, 1024, 1024, 3072, 1024>;
    auto kQKT = gemm8p<3, 3072, 3072, 2048, 1024>;
    auto kPV  = gemm8p<4, 2048, 2048, 1024, 2048>;
    (void)hipFuncSetAttribute(reinterpret_cast<const void*>(kQKV),
                              hipFuncAttributeMaxDynamicSharedMemorySize, LDSB);
    (void)hipFuncSetAttribute(reinterpret_cast<const void*>(kQKT),
                              hipFuncAttributeMaxDynamicSharedMemorySize, LDSB);
    (void)hipFuncSetAttribute(reinterpret_cast<const void*>(kPV),
                              hipFuncAttributeMaxDynamicSharedMemorySize, LDSB);

    // fused x-convert + W-transpose
    cvt_fused<<<dim3(5120), 256, 0, stream>>>(x, xb, W, Wtb);

    // qkv = x @ W + b : grid 12 x 64 ; V third written transposed into Vtb
    kQKV<<<dim3(12 * 64), 512, LDSB, stream>>>(xb, 0, Wtb, 0, qkvb, 0,
                                               bias, nullptr, Vtb, 1.0f, 12, 64);

    if (full) {
        // Sb = exp(Q K^T * sc), row sums -> Ps
        kQKT<<<dim3(8 * 8 * 8), 512, LDSB, stream>>>(
            qkvb, (long long)S * N3, qkvb + E, (long long)S * N3,
            Sb, (long long)S * S, nullptr, Ps, nullptr, sc, 8, 8);
        // out = (Sb @ Vt^T) * (1/rowsum)  — denominators folded into epilogue
        kPV<<<dim3(4 * 8 * 8), 512, LDSB, stream>>>(
            Sb, (long long)S * S, Vtb, (long long)E * S,
            out, (long long)S * E, nullptr, Ps, nullptr, 1.0f, 4, 8);
    } else {
        for (int b = 0; b < B; ++b) {
            const u16* Qb = qkvb + (size_t)b * S * N3;
            kQKT<<<dim3(8 * 8), 512, LDSB, stream>>>(
                Qb, 0, Qb + E, 0, Sb, 0, nullptr, Ps, nullptr, sc, 8, 8);
            kPV<<<dim3(4 * 8), 512, LDSB, stream>>>(
                Sb, 0, Vtb + (size_t)b * E * S, 0,
                out + (size_t)b * S * E, 0, nullptr, Ps, nullptr, 1.0f, 4, 8);
        }
    }
}

// Round 15
// 258.507 us; speedup vs baseline: 1.3294x; 1.0366x over previous
//
#include <hip/hip_runtime.h>

typedef unsigned short u16;
typedef unsigned int u32;
typedef __attribute__((ext_vector_type(8))) short short8;
typedef __attribute__((ext_vector_type(4))) short short4v;
typedef __attribute__((ext_vector_type(4))) float f32x4;

__device__ __forceinline__ u16 f2bf(float f) {
    u32 u = __float_as_uint(f);
    u32 r = (u + 0x7fffu + ((u >> 16) & 1u)) >> 16;   // RNE
    return (u16)r;
}
__device__ __forceinline__ float bf2f(u16 h) {
    return __uint_as_float(((u32)h) << 16);
}

__device__ __forceinline__ void gload_lds16(const void* g, void* l) {
    __builtin_amdgcn_global_load_lds((const __attribute__((address_space(1))) void*)g,
                                     (__attribute__((address_space(3))) void*)l, 16, 0, 0);
}

// pinned barrier: sched_barrier(0) walls are LOAD-BEARING (R13 A/B: removing
// them regressed GEMMs 105->141 us; compiler reordering breaks the phase
// discipline). Do not relax.
#define BARRIER() do { __builtin_amdgcn_sched_barrier(0); __builtin_amdgcn_s_barrier(); __builtin_amdgcn_sched_barrier(0); } while (0)
#define VMCNT(N)  asm volatile("s_waitcnt vmcnt(" #N ")" ::: "memory")

// stage one 128-row half (2 global_load_lds per thread; dest linear, src inverse-swizzled)
#define STAGE(ptr, LDG, LOFF, RBASE, kelem) \
    do { gload_lds16((ptr) + (size_t)(RBASE) * (LDG) + (kelem),        lds + (LOFF) + ((RBASE) + (wid << 3)) * 128); \
         gload_lds16((ptr) + (size_t)((RBASE) + 64) * (LDG) + (kelem), lds + (LOFF) + ((RBASE) + 64 + (wid << 3)) * 128); } while (0)

template<int ROFF, int QH>
__device__ __forceinline__ void ld_a(short8 (&a)[4][2], const char* lds, int arow, int c0, int c1) {
    #pragma unroll
    for (int mf = 0; mf < 4; ++mf) {
        a[mf][0] = *(const short8*)(lds + ROFF + QH * 16384 + mf * 2048 + arow + c0);
        a[mf][1] = *(const short8*)(lds + ROFF + QH * 16384 + mf * 2048 + arow + c1);
    }
}
template<int ROFF, int QH>
__device__ __forceinline__ void ld_b(short8 (&b)[2][2], const char* lds, int brow, int c0, int c1) {
    #pragma unroll
    for (int nf = 0; nf < 2; ++nf) {
        b[nf][0] = *(const short8*)(lds + ROFF + QH * 16384 + nf * 2048 + brow + c0);
        b[nf][1] = *(const short8*)(lds + ROFF + QH * 16384 + nf * 2048 + brow + c1);
    }
}

template<int QM, int QN>
__device__ __forceinline__ void mfq(f32x4 (&acc)[2][4][2][2], short8 (&a)[4][2], short8 (&b)[2][2]) {
    __builtin_amdgcn_s_setprio(1);
    #pragma unroll
    for (int mf = 0; mf < 4; ++mf)
        #pragma unroll
        for (int nf = 0; nf < 2; ++nf) {
            acc[QM][mf][QN][nf] = __builtin_amdgcn_mfma_f32_16x16x32_bf16(a[mf][0], b[nf][0], acc[QM][mf][QN][nf], 0, 0, 0);
            acc[QM][mf][QN][nf] = __builtin_amdgcn_mfma_f32_16x16x32_bf16(a[mf][1], b[nf][1], acc[QM][mf][QN][nf], 0, 0, 0);
        }
    __builtin_amdgcn_s_setprio(0);
}

// ---------------------------------------------------------------------------
// 256x256 8-phase bf16 GEMM — best measured configuration (R12, 260.2 us).
// A [M][K] rm, B [N][K] rm. Snake Q00->Q01->Q11->Q10 per K-tile; B halves in regs.
// Stage slots: ph1: buf1.Ah1[T+1]  ph3: buf0.Bh0[T+2]  ph4: buf0.Bh1 ;gate(4)
//   ph5: buf0.Ah0  ph6: buf0.Ah1  ph7: buf1.Bh0+Bh1[T+3]  ph8: buf1.Ah0 ;gate(6)
// Gates at end of phase, published by that phase's barrier (FIFO-verified).
// LDS 128 KiB: buf0A@0 buf0B@32768 buf1A@65536 buf1B@98304, [256][64] each,
// 16B-slot swizzle: LDS[row][s] = G[row][s ^ (row&7)].
// Register ledger: acc 128 (AGPR) + 124 VGPR = 252/256 -> no headroom for
// fragment double-buffering (R8 spill); phase reads are WAR-serialized vs
// MFMA — the structural plateau at ~42% MfmaUtil.
// EPI: 0 = QKV: cols<2048 -> bf16 qkv + bias ; cols>=2048 -> V transposed to vt
//      3 = bf16 out = exp(acc*scale), row-sums -> ps[(z*2048+row)*GX+bx] (QKT)
//      4 = f32 out = acc * (1/sum(ps[row][0..7]))  (PV; dinv computed in-block)
// ---------------------------------------------------------------------------
template<int EPI, int LDA, int LDB, int LDC, int K>
__global__ __launch_bounds__(512, 2)
void gemm8p(const u16* __restrict__ A, long long sA,
            const u16* __restrict__ B, long long sB,
            void* __restrict__ Cv, long long sC,
            const float* __restrict__ bias, float* __restrict__ ps,
            u16* __restrict__ vt, float scale, int GX, int GY)
{
    extern __shared__ char lds[];
    const int tid  = threadIdx.x;
    const int wid  = tid >> 6;
    const int lane = tid & 63;

    // bijective XCD swizzle (all grids are multiples of 8)
    const int nwg = gridDim.x;
    int bid = blockIdx.x;
    bid = (bid & 7) * (nwg >> 3) + (bid >> 3);
    const int bx  = bid % GX;
    const int rem = bid / GX;
    const int by  = rem % GY;
    const long long z = rem / GY;

    const int bm = by * 256, bn = bx * 256;
    const u16* Atile = A + z * sA + (size_t)bm * LDA;
    const u16* Btile = B + z * sB + (size_t)bn * LDB;

    const int wm = wid >> 2, wn = wid & 3;
    const int l15   = lane & 15;
    const int lxor  = (lane & 7) << 4;
    const int khi   = (lane >> 4) << 4;
    const int colk0 = khi ^ lxor;
    const int colk1 = (64 + khi) ^ lxor;
    const int arow  = (wm * 64 + l15) * 128;
    const int brow  = (wn * 32 + l15) * 128;

    const int swz = ((lane & 7) ^ (lane >> 3)) << 3;   // inverse-swizzled src col (elems)
    const u16* pA = Atile + (size_t)((wid << 3) + (lane >> 3)) * LDA + swz;
    const u16* pB = Btile + (size_t)((wid << 3) + (lane >> 3)) * LDB + swz;

    f32x4 acc[2][4][2][2];
    #pragma unroll
    for (int i = 0; i < 2; ++i)
        #pragma unroll
        for (int m = 0; m < 4; ++m)
            #pragma unroll
            for (int j = 0; j < 2; ++j)
                #pragma unroll
                for (int n = 0; n < 2; ++n)
                    acc[i][m][j][n] = (f32x4){0.f, 0.f, 0.f, 0.f};

    // prologue: buf0 <- T0 (8 loads), buf1 <- T1 {Ah0, Bh0, Bh1} (6 loads)
    STAGE(pA, LDA, 0,     0,   0);  STAGE(pA, LDA, 0,     128, 0);
    STAGE(pB, LDB, 32768, 0,   0);  STAGE(pB, LDB, 32768, 128, 0);
    STAGE(pA, LDA, 65536, 0,   64);
    STAGE(pB, LDB, 98304, 0,   64); STAGE(pB, LDB, 98304, 128, 64);
    VMCNT(6);
    BARRIER();

    short8 a[4][2], b0[2][2], b1[2][2];
    const int NI = K >> 7;     // two 64-wide K-tiles per iteration

    for (int it = 0; it < NI; ++it) {
        const bool more = (it + 1 < NI);
        const int kc1 = it * 128 + 64;     // current pair's 2nd tile (buf1)
        const int kn  = it * 128 + 128;    // T+2 (-> buf0)
        const int kn2 = kn + 64;           // T+3 (-> buf1)

        // ph1: Q00 buf0 ; stage buf1.Ah1 (completes T+1)
        ld_a<0, 0>(a, lds, arow, colk0, colk1);
        ld_b<32768, 0>(b0, lds, brow, colk0, colk1);
        STAGE(pA, LDA, 65536, 128, kc1);
        BARRIER(); mfq<0, 0>(acc, a, b0);
        // ph2: Q01 buf0
        ld_b<32768, 1>(b1, lds, brow, colk0, colk1);
        BARRIER(); mfq<0, 1>(acc, a, b1);
        // ph3: Q11 buf0 ; stage buf0.Bh0 <- T+2
        ld_a<0, 1>(a, lds, arow, colk0, colk1);
        if (more) STAGE(pB, LDB, 32768, 0, kn);
        BARRIER(); mfq<1, 1>(acc, a, b1);
        // ph4: Q10 buf0 ; stage buf0.Bh1 <- T+2 ; end-gate buf1(T+1)
        if (more) { STAGE(pB, LDB, 32768, 128, kn); VMCNT(4); }
        else      { VMCNT(0); }
        BARRIER(); mfq<1, 0>(acc, a, b0);
        // ph5: Q00 buf1 ; stage buf0.Ah0 <- T+2
        ld_a<65536, 0>(a, lds, arow, colk0, colk1);
        ld_b<98304, 0>(b0, lds, brow, colk0, colk1);
        if (more) STAGE(pA, LDA, 0, 0, kn);
        BARRIER(); mfq<0, 0>(acc, a, b0);
        // ph6: Q01 buf1 ; stage buf0.Ah1 <- T+2
        ld_b<98304, 1>(b1, lds, brow, colk0, colk1);
        if (more) STAGE(pA, LDA, 0, 128, kn);
        BARRIER(); mfq<0, 1>(acc, a, b1);
        // ph7: Q11 buf1 ; stage buf1.Bh0+Bh1 <- T+3
        ld_a<65536, 1>(a, lds, arow, colk0, colk1);
        if (more) { STAGE(pB, LDB, 98304, 0, kn2); STAGE(pB, LDB, 98304, 128, kn2); }
        BARRIER(); mfq<1, 1>(acc, a, b1);
        // ph8: Q10 buf1 ; stage buf1.Ah0 <- T+3 ; end-gate buf0(T+2)
        if (more) STAGE(pA, LDA, 65536, 0, kn2);
        VMCNT(6);                          // no-op on final iter (queue empty)
        BARRIER(); mfq<1, 0>(acc, a, b0);
    }

    // epilogue. C/D map (m89): col = lane&15, row = 4*(lane>>4)+reg
    const int r0 = (lane >> 4) * 4;
    const int cc = lane & 15;

    if (EPI == 3) {
        BARRIER();                       // all waves done with buf LDS -> reuse
        float* rs = (float*)lds;         // [4][256]
        u16* C = (u16*)Cv + z * sC;
        float rsum[2][4][4];
        #pragma unroll
        for (int qm = 0; qm < 2; ++qm)
            #pragma unroll
            for (int mf = 0; mf < 4; ++mf)
                #pragma unroll
                for (int r = 0; r < 4; ++r) rsum[qm][mf][r] = 0.f;
        #pragma unroll
        for (int qn = 0; qn < 2; ++qn)
            #pragma unroll
            for (int nf = 0; nf < 2; ++nf) {
                const int col = bn + qn * 128 + wn * 32 + nf * 16 + cc;
                #pragma unroll
                for (int qm = 0; qm < 2; ++qm)
                    #pragma unroll
                    for (int mf = 0; mf < 4; ++mf) {
                        const int row = bm + qm * 128 + wm * 64 + mf * 16 + r0;
                        #pragma unroll
                        for (int r = 0; r < 4; ++r) {
                            const float e = __expf(acc[qm][mf][qn][nf][r] * scale);
                            const u16 eb = f2bf(e);
                            C[(size_t)(row + r) * LDC + col] = eb;
                            rsum[qm][mf][r] += bf2f(eb);
                        }
                    }
            }
        #pragma unroll
        for (int qm = 0; qm < 2; ++qm)
            #pragma unroll
            for (int mf = 0; mf < 4; ++mf)
                #pragma unroll
                for (int r = 0; r < 4; ++r) {
                    float v = rsum[qm][mf][r];
                    v += __shfl_xor(v, 1); v += __shfl_xor(v, 2);
                    v += __shfl_xor(v, 4); v += __shfl_xor(v, 8);
                    if (cc == 0)
                        rs[wn * 256 + qm * 128 + wm * 64 + mf * 16 + r0 + r] = v;
                }
        __syncthreads();
        if (tid < 256) {
            const float s = rs[tid] + rs[256 + tid] + rs[512 + tid] + rs[768 + tid];
            ps[((size_t)z * 2048 + bm + tid) * GX + bx] = s;
        }
        return;
    }

    if (EPI == 4) {
        // per-block softmax denominators from ps[row][0..7] -> LDS
        BARRIER();                       // all waves done with buf LDS -> reuse
        float* di = (float*)lds;         // [256]
        if (tid < 256) {
            const float* p = ps + ((size_t)z * 2048 + bm + tid) * 8;
            const float s = ((p[0] + p[1]) + (p[2] + p[3])) + ((p[4] + p[5]) + (p[6] + p[7]));
            di[tid] = 1.0f / s;
        }
        __syncthreads();
        float* C = (float*)Cv + z * sC;
        #pragma unroll
        for (int qn = 0; qn < 2; ++qn)
            #pragma unroll
            for (int nf = 0; nf < 2; ++nf) {
                const int col = bn + qn * 128 + wn * 32 + nf * 16 + cc;
                #pragma unroll
                for (int qm = 0; qm < 2; ++qm)
                    #pragma unroll
                    for (int mf = 0; mf < 4; ++mf) {
                        const int ro = qm * 128 + wm * 64 + mf * 16 + r0;
                        #pragma unroll
                        for (int r = 0; r < 4; ++r)
                            C[(size_t)(bm + ro + r) * LDC + col] = acc[qm][mf][qn][nf][r] * di[ro + r];
                    }
            }
        return;
    }

    if (EPI == 0 && bn >= 2048) {
        // V block: write transposed straight into Vt [B][1024][2048]
        #pragma unroll
        for (int qn = 0; qn < 2; ++qn)
            #pragma unroll
            for (int nf = 0; nf < 2; ++nf) {
                const int col = bn + qn * 128 + wn * 32 + nf * 16 + cc;
                const float badd = bias[col];
                const int e = col - 2048;
                #pragma unroll
                for (int qm = 0; qm < 2; ++qm)
                    #pragma unroll
                    for (int mf = 0; mf < 4; ++mf) {
                        const int row = bm + qm * 128 + wm * 64 + mf * 16 + r0;
                        short4v o;
                        #pragma unroll
                        for (int r = 0; r < 4; ++r)
                            o[r] = (short)f2bf(acc[qm][mf][qn][nf][r] + badd);
                        *(short4v*)&vt[((size_t)(row >> 11) << 21) + (size_t)e * 2048 + (row & 2047)] = o;
                    }
            }
        return;
    }

    // EPI == 0, Q/K columns
    #pragma unroll
    for (int qn = 0; qn < 2; ++qn)
        #pragma unroll
        for (int nf = 0; nf < 2; ++nf) {
            const int col = bn + qn * 128 + wn * 32 + nf * 16 + cc;
            const float badd = bias[col];
            #pragma unroll
            for (int qm = 0; qm < 2; ++qm)
                #pragma unroll
                for (int mf = 0; mf < 4; ++mf) {
                    const int row = bm + qm * 128 + wm * 64 + mf * 16 + r0;
                    #pragma unroll
                    for (int r = 0; r < 4; ++r) {
                        const float v = acc[qm][mf][qn][nf][r] + badd;
                        ((u16*)Cv + z * sC)[(size_t)(row + r) * LDC + col] = f2bf(v);
                    }
                }
        }
}

// ---------------------------------------------------------------------------
// fused input prep, ILP version:
//   blocks [0,4096): convert x f32->bf16, 2 chunks/thread, ALL loads issued
//     before any convert/store (64 B in flight per thread).
//   blocks [4096,7168): transpose-convert W [1024][3072] -> Wt [3072][1024].
__global__ __launch_bounds__(256)
void cvt_fused(const float* __restrict__ x, u16* __restrict__ xb,
               const float* __restrict__ W, u16* __restrict__ Wt)
{
    __shared__ u16 T[32][33];
    const int blk = blockIdx.x;
    const int tid = threadIdx.x;
    if (blk < 4096) {
        const float4* p = (const float4*)x;
        const int i0 = blk * 256 + tid;          // float8-chunk index; stride 1048576
        float4 a0 = p[2 * i0],             b0v = p[2 * i0 + 1];
        float4 a1 = p[2 * (i0 + 1048576)], b1v = p[2 * (i0 + 1048576) + 1];
        short8 o0, o1;
        o0[0] = (short)f2bf(a0.x); o0[1] = (short)f2bf(a0.y);
        o0[2] = (short)f2bf(a0.z); o0[3] = (short)f2bf(a0.w);
        o0[4] = (short)f2bf(b0v.x); o0[5] = (short)f2bf(b0v.y);
        o0[6] = (short)f2bf(b0v.z); o0[7] = (short)f2bf(b0v.w);
        o1[0] = (short)f2bf(a1.x); o1[1] = (short)f2bf(a1.y);
        o1[2] = (short)f2bf(a1.z); o1[3] = (short)f2bf(a1.w);
        o1[4] = (short)f2bf(b1v.x); o1[5] = (short)f2bf(b1v.y);
        o1[6] = (short)f2bf(b1v.z); o1[7] = (short)f2bf(b1v.w);
        ((short8*)xb)[i0] = o0;
        ((short8*)xb)[i0 + 1048576] = o1;
        return;
    }
    const int wb = blk - 4096;
    const int c0 = (wb % 96) * 32;
    const int r0 = (wb / 96) * 32;
    const int tr = tid >> 3;
    const int tc = (tid & 7) * 4;
    const float4 v = *(const float4*)&W[(size_t)(r0 + tr) * 3072 + c0 + tc];
    T[tr][tc + 0] = f2bf(v.x); T[tr][tc + 1] = f2bf(v.y);
    T[tr][tc + 2] = f2bf(v.z); T[tr][tc + 3] = f2bf(v.w);
    __syncthreads();
    short4v o;
    o[0] = (short)T[tc + 0][tr]; o[1] = (short)T[tc + 1][tr];
    o[2] = (short)T[tc + 2][tr]; o[3] = (short)T[tc + 3][tr];
    *(short4v*)&Wt[(size_t)(c0 + tr) * 1024 + r0 + tc] = o;
}

// ---------------------------------------------------------------------------
extern "C" void kernel_launch(void* const* d_in, const int* in_sizes, int n_in,
                              void* d_out, int out_size, void* d_ws, size_t ws_size,
                              hipStream_t stream) {
    const float* x    = (const float*)d_in[0];   // [8,2048,1024]
    const float* W    = (const float*)d_in[1];   // [1024,3072]
    const float* bias = (const float*)d_in[2];   // [3072]
    float* out = (float*)d_out;                  // [8,2048,1024] f32

    const int B = 8, S = 2048, E = 1024, N3 = 3072;
    const int M = B * S;                         // 16384

    char* ws = (char*)d_ws;
    u16* xb   = (u16*)ws;                          // 32 MiB  [M][E]
    u16* Wtb  = (u16*)(ws + 33554432);             //  6 MiB  [3072][1024]
    u16* qkvb = (u16*)(ws + 39845888);             // 96 MiB  [M][3072] (Q,K thirds used)
    u16* Vtb  = (u16*)(ws + 140509184);            // 32 MiB  [B][1024][2048]
    u16* Sb   = (u16*)(ws + 174063616);            // E=exp scores

    const size_t sbFull = (size_t)B * S * S * 2;          // 64 MiB
    const size_t sbOne  = (size_t)S * S * 2;              //  8 MiB
    const size_t psFull = (size_t)M * 8 * sizeof(float);  // 512 KiB
    const size_t need_full = 174063616ull + sbFull + psFull;
    const bool full = ws_size >= need_full;

    float* Ps = (float*)(ws + 174063616 + (full ? sbFull : sbOne));

    const float sc = 1.0f / 32.0f;
    const int LDSB = 131072;

    // instantiations: <EPI, LDA, LDB, LDC, K>
    auto kQKV = gemm8p<0, 1024, 1024, 3072, 1024>;
    auto kQKT = gemm8p<3, 3072, 3072, 2048, 1024>;
    auto kPV  = gemm8p<4, 2048, 2048, 1024, 2048>;
    (void)hipFuncSetAttribute(reinterpret_cast<const void*>(kQKV),
                              hipFuncAttributeMaxDynamicSharedMemorySize, LDSB);
    (void)hipFuncSetAttribute(reinterpret_cast<const void*>(kQKT),
                              hipFuncAttributeMaxDynamicSharedMemorySize, LDSB);
    (void)hipFuncSetAttribute(reinterpret_cast<const void*>(kPV),
                              hipFuncAttributeMaxDynamicSharedMemorySize, LDSB);

    // fused x-convert + W-transpose (ILP version)
    cvt_fused<<<dim3(7168), 256, 0, stream>>>(x, xb, W, Wtb);

    // qkv = x @ W + b : grid 12 x 64 ; V third written transposed into Vtb
    kQKV<<<dim3(12 * 64), 512, LDSB, stream>>>(xb, 0, Wtb, 0, qkvb, 0,
                                               bias, nullptr, Vtb, 1.0f, 12, 64);

    if (full) {
        // Sb = exp(Q K^T * sc), row sums -> Ps
        kQKT<<<dim3(8 * 8 * 8), 512, LDSB, stream>>>(
            qkvb, (long long)S * N3, qkvb + E, (long long)S * N3,
            Sb, (long long)S * S, nullptr, Ps, nullptr, sc, 8, 8);
        // out = (Sb @ Vt^T) * (1/rowsum)  — denominators folded into epilogue
        kPV<<<dim3(4 * 8 * 8), 512, LDSB, stream>>>(
            Sb, (long long)S * S, Vtb, (long long)E * S,
            out, (long long)S * E, nullptr, Ps, nullptr, 1.0f, 4, 8);
    } else {
        for (int b = 0; b < B; ++b) {
            const u16* Qb = qkvb + (size_t)b * S * N3;
            kQKT<<<dim3(8 * 8), 512, LDSB, stream>>>(
                Qb, 0, Qb + E, 0, Sb, 0, nullptr, Ps, nullptr, sc, 8, 8);
            kPV<<<dim3(4 * 8), 512, LDSB, stream>>>(
                Sb, 0, Vtb + (size_t)b * E * S, 0,
                out + (size_t)b * S * E, 0, nullptr, Ps, nullptr, 1.0f, 4, 8);
        }
    }
}